// Round 2
// 102.450 us; speedup vs baseline: 1.0307x; 1.0307x over previous
//
#include <hip/hip_runtime.h>
#include <math.h>

#define P      512
#define NA     180
#define NB     4
#define FOFF4  64               // leading zero-pad floats per angle row (16 positions x 4 batches)
#define FS4    (FOFF4 + 4 * P + FOFF4)   // 2176 floats: pad + 4-batch-interleaved data + pad
#define GUARD  512              // float guard before fil2 for window-staging underreach
#define TS     16               // backprojection pixel tile (16x16 -> 1024 blocks, 4/CU)
#define WPOS   28               // window positions per angle
#define WSF4   (WPOS * 4)       // 112 floats per angle (28 positions x 4 batches)
#define ASEG   60               // angles staged per LDS round (3 segments)
#define NTILES (32 * 32)

#if __has_builtin(__builtin_amdgcn_fractf)
#define FRACT(x) __builtin_amdgcn_fractf(x)
#else
#define FRACT(x) ((x) - floorf(x))
#endif

typedef float f4 __attribute__((ext_vector_type(4), aligned(16)));

// ---------------------------------------------------------------------------
// K0 (512 x 64): ff[o] = 2*(0.25 + sum_m fodd[m] cos(2pi o(2m+1)/512)) * sinc.
// (sct generation moved into ir_filter's table block.)
// ---------------------------------------------------------------------------
__global__ __launch_bounds__(64) void ir_spectrum(float* __restrict__ ffg) {
    const int o = blockIdx.x;
    const int t = threadIdx.x;
    double s = 0.0;
    #pragma unroll
    for (int i = 0; i < 4; ++i) {
        const int m = t + 64 * i;
        const int idx = 2 * m + 1;
        const int n = (idx < 256) ? idx : (512 - idx);
        const double fv = -1.0 / ((M_PI * n) * (M_PI * n));
        const int ph = (o * idx) & 511;
        s += fv * cos((2.0 * M_PI / 512.0) * (double)ph);
    }
    #pragma unroll
    for (int off = 32; off; off >>= 1) s += __shfl_down(s, off, 64);
    if (t == 0) {
        double ff = 0.5 + 2.0 * s;
        if (o > 0) {
            const double freq = (o <= 256) ? (double)o / 512.0 : ((double)o - 512.0) / 512.0;
            const double w = M_PI * freq;   // sinc even; fftfreq sign irrelevant
            ff *= sin(w) / w;
        }
        ffg[o] = (float)ff;
    }
}

// ---------------------------------------------------------------------------
// K1 (512 x 64): hr[o] = (1/512) sum_k ff[k] cos(2pi k o / 512).
// ---------------------------------------------------------------------------
__global__ __launch_bounds__(64) void ir_impulse(const float* __restrict__ ffg,
                                                 float* __restrict__ hr) {
    const int o = blockIdx.x;
    const int t = threadIdx.x;
    double s = 0.0;
    #pragma unroll
    for (int i = 0; i < 8; ++i) {
        const int k = t + 64 * i;
        const int ph = (o * k) & 511;
        s += (double)ffg[k] * cos((2.0 * M_PI / 512.0) * (double)ph);
    }
    #pragma unroll
    for (int off = 32; off; off >>= 1) s += __shfl_down(s, off, 64);
    if (t == 0) hr[o] = (float)(s / 512.0);
}

// ---------------------------------------------------------------------------
// K2: one 512-thread block per angle does the circular conv for ALL 4 batches
// (y==0), or builds the sct + window-base tables (y==1). Conv: filtered[n] =
// sum_j hr[j] * row[(n-j) mod 512], hr via s_load, rolling register window ->
// ONE ds_read_b128 per K-step per thread. Output is 4-batch interleaved
// (float index FOFF4 + 4*pos + b), staged through LDS so the global stores
// are fully-coalesced dwordx4 (the old direct path was a stride-16 scatter).
// ---------------------------------------------------------------------------
__global__ __launch_bounds__(512) void ir_filter(const float* __restrict__ sino,
                                                 const float* __restrict__ hr,
                                                 float* __restrict__ fil2,
                                                 float2* __restrict__ sct,
                                                 float* __restrict__ qbt) {
    __shared__ __align__(16) float row2[4][2 * P];
    __shared__ __align__(16) float sOut[4 * P];
    const int a = blockIdx.x;
    const int t = threadIdx.x;

    if (blockIdx.y == 1) {            // sct + window-base table for angle a
        const float th = (float)a * (float)(M_PI / (double)(NA - 1));
        const float s = sinf(th);     // s >= 0 on [0,pi]
        const float c = cosf(th);
        if (t == 0) sct[a] = make_float2(s, c);
        #pragma unroll
        for (int i = 0; i < 2; ++i) {
            const int tile = t + 512 * i;          // by*32+bx
            const int bx = tile & 31, by = tile >> 5;
            const float xlo = (float)(240 - 16 * bx);   // min x over tile
            const float ylo = (float)(16 * by - 256);
            const float yhi = (float)(16 * by - 241);
            const float pmin = fmaf(s, xlo, fminf(c * ylo, c * yhi) + 256.0f);
            const int base = ((int)floorf(pmin) - 2) & ~1;  // even, fp-slop safety
            qbt[tile * NA + a] = (float)(256 - base);
        }
        return;
    }

    const int b = t >> 7;             // batch 0..3
    const int tt = t & 127;           // outputs 4tt..4tt+3

    const float* src = sino + ((size_t)b * NA + a) * P;
    const float4 v = *(const float4*)(src + 4 * tt);
    *(float4*)&row2[b][4 * tt] = v;
    *(float4*)&row2[b][4 * tt + P] = v;
    __syncthreads();

    const int base0 = P + 4 * tt;
    float4 A = *(const float4*)&row2[b][base0];    // window floats w[0..3]
    float a0 = 0.f, a1 = 0.f, a2 = 0.f, a3 = 0.f;
    #pragma unroll 4
    for (int J = 0; J < P; J += 4) {
        const float4 Bv = *(const float4*)&row2[b][base0 - J - 4];  // w[-4..-1]
        const float h0 = hr[J], h1 = hr[J + 1], h2v = hr[J + 2], h3 = hr[J + 3];
        a0 = fmaf(h0, A.x, a0); a0 = fmaf(h1, Bv.w, a0); a0 = fmaf(h2v, Bv.z, a0); a0 = fmaf(h3, Bv.y, a0);
        a1 = fmaf(h0, A.y, a1); a1 = fmaf(h1, A.x, a1); a1 = fmaf(h2v, Bv.w, a1); a1 = fmaf(h3, Bv.z, a1);
        a2 = fmaf(h0, A.z, a2); a2 = fmaf(h1, A.y, a2); a2 = fmaf(h2v, A.x, a2); a2 = fmaf(h3, Bv.w, a2);
        a3 = fmaf(h0, A.w, a3); a3 = fmaf(h1, A.z, a3); a3 = fmaf(h2v, A.y, a3); a3 = fmaf(h3, A.x, a3);
        A = Bv;                                    // slide the register window
    }
    // interleave via LDS: float index in data region = 4*pos + b, pos = 4tt+d
    const int o0 = 16 * tt + b;
    sOut[o0]      = a0;
    sOut[o0 + 4]  = a1;
    sOut[o0 + 8]  = a2;
    sOut[o0 + 12] = a3;
    __syncthreads();

    float* frow = fil2 + (size_t)a * FS4;
    *(f4*)(frow + FOFF4 + 4 * t) = *(const f4*)(sOut + 4 * t);   // coalesced
    if (t < FOFF4) {                  // zero pads (ws re-poisoned every call)
        frow[t] = 0.f;
        frow[FOFF4 + 4 * P + t] = 0.f;
    }
}

// ---------------------------------------------------------------------------
// K3: backprojection, ALL 4 BATCHES per block, 16x16 tile (1024 blocks).
// Angle-segmented 26.9 KB window buffer, 4-batch interleave: the q/j/frac
// address math runs ONCE per pixel (was once per pair), and the two 16B LDS
// reads per angle (positions j, j+1) feed 8 bilinear taps. Per-angle
// constants (s, c, qb) are wave-uniform s_loads from global tables.
// ---------------------------------------------------------------------------
__global__ __launch_bounds__(256) void ir_backproject(const float* __restrict__ fil2,
                                                      const float2* __restrict__ sct,
                                                      const float* __restrict__ qbt,
                                                      float* __restrict__ out) {
    __shared__ __align__(16) float win[ASEG * WSF4 + 16];   // 26.9 KB + slack

    const int t = threadIdx.x;
    const int w0 = blockIdx.x * TS, h0 = blockIdx.y * TS;
    const float* qrow = qbt + (blockIdx.y * 32 + blockIdx.x) * NA;  // this tile's bases

    const int w = w0 + (t & 15);
    const int h = h0 + (t >> 4);

    const int ix = 255 - w;              // reversed x axis
    const int iy = h - 256;
    const int m = (ix * ix + iy * iy) <= 256 * 256;

    float* o0 = out + (size_t)h * P + w;

    if (__syncthreads_count(m) == 0) {   // tile fully outside circle
        o0[0] = 0.f;
        o0[P * P] = 0.f;
        o0[2 * P * P] = 0.f;
        o0[3 * P * P] = 0.f;
        return;
    }

    const float xf = (float)ix;
    const float yf = (float)iy;
    float acc0 = 0.f, acc1 = 0.f, acc2 = 0.f, acc3 = 0.f;

    #pragma unroll
    for (int seg = 0; seg < 3; ++seg) {
        const int A0 = seg * ASEG;

        // Phase B: stage this segment's 4-batch windows (16B-aligned chunks)
        for (int idx = t; idx < ASEG * WPOS; idx += 256) {
            const int al = idx / WPOS;
            const int i = idx - al * WPOS;
            const int a = A0 + al;
            const int base = 256 - (int)qrow[a];          // lane-varying -> v-load
            const int off = a * FS4 + FOFF4 + 4 * (base + i);  // 16B aligned
            const f4 vv = *(const f4*)(fil2 + off);
            *(f4*)(win + al * WSF4 + 4 * i) = vv;
        }
        __syncthreads();

        // Phase C: q = p - base in [~2, 27); j = trunc(q); f4 at 4j holds all
        // 4 batches at position j; second f4 at 4j+4 -> both taps, 4 batches.
        #pragma unroll 4
        for (int al = 0; al < ASEG; ++al) {
            const float2 sc = sct[A0 + al];               // wave-uniform -> s_load
            const float qb = qrow[A0 + al];               // wave-uniform -> s_load
            const float q = fmaf(xf, sc.x, fmaf(yf, sc.y, qb));
            const int j = (int)q;
            const float fr = FRACT(q);
            const float omf = 1.f - fr;
            const f4 W0 = *(const f4*)(win + al * WSF4 + 4 * j);
            const f4 W1 = *(const f4*)(win + al * WSF4 + 4 * j + 4);
            acc0 = fmaf(omf, W0.x, fmaf(fr, W1.x, acc0));
            acc1 = fmaf(omf, W0.y, fmaf(fr, W1.y, acc1));
            acc2 = fmaf(omf, W0.z, fmaf(fr, W1.z, acc2));
            acc3 = fmaf(omf, W0.w, fmaf(fr, W1.w, acc3));
        }
        if (seg < 2) __syncthreads();    // protect win before restage (uniform)
    }

    const float scale = (float)(M_PI / (2.0 * NA));
    o0[0]         = m ? acc0 * scale : 0.f;
    o0[P * P]     = m ? acc1 * scale : 0.f;
    o0[2 * P * P] = m ? acc2 * scale : 0.f;
    o0[3 * P * P] = m ? acc3 * scale : 0.f;
}

// ---------------------------------------------------------------------------
extern "C" void kernel_launch(void* const* d_in, const int* in_sizes, int n_in,
                              void* d_out, int out_size, void* d_ws, size_t ws_size,
                              hipStream_t stream) {
    const float* sino = (const float*)d_in[0];
    float* out = (float*)d_out;
    float* ws = (float*)d_ws;

    float* ffg   = ws;                        // 512
    float* hr    = ws + 512;                  // 512
    float2* sct  = (float2*)(ws + 1024);      // 180 float2 -> 512-float slot
    float* qbt   = ws + 1536;                 // 1024 tiles * 180 floats
    float* fil2  = ws + 1536 + NTILES * NA + GUARD;   // 180*2176 floats, 16B aligned

    ir_spectrum<<<P, 64, 0, stream>>>(ffg);
    ir_impulse<<<P, 64, 0, stream>>>(ffg, hr);

    dim3 gridF(NA, 2);                        // y=0: conv (all 4 batches); y=1: sct+qbt
    ir_filter<<<gridF, 512, 0, stream>>>(sino, hr, fil2, sct, qbt);

    dim3 gridB(P / TS, P / TS, 1);            // 1024 blocks, 4 batches in-block
    ir_backproject<<<gridB, 256, 0, stream>>>(fil2, sct, qbt, out);
}

// Round 3
// 97.394 us; speedup vs baseline: 1.0842x; 1.0519x over previous
//
#include <hip/hip_runtime.h>
#include <math.h>

#define P      512
#define NA     180
#define NB     4
#define FOFF4  64               // leading zero-pad floats per angle row (16 positions x 4 batches)
#define FS4    (FOFF4 + 4 * P + FOFF4)   // 2176 floats: pad + 4-batch-interleaved data + pad
#define GUARD  512              // float guard before fil2 for window-staging underreach
#define TS     16               // backprojection pixel tile (16x16 -> 1024 blocks, 4/CU)
#define WPOS   28               // window positions per angle
#define WSF4   (WPOS * 4)       // 112 floats per angle (28 positions x 4 batches)
#define ASEG   60               // angles staged per LDS round (3 segments)
#define NTILES (32 * 32)

#if __has_builtin(__builtin_amdgcn_fractf)
#define FRACT(x) __builtin_amdgcn_fractf(x)
#else
#define FRACT(x) ((x) - floorf(x))
#endif

typedef float f4 __attribute__((ext_vector_type(4), aligned(16)));

// ===========================================================================
// Compile-time tables. hr (impulse response of the Shepp-Logan ramp filter)
// and the angle sin/cos table are input-independent; the old ir_spectrum /
// ir_impulse dispatches are replaced by constexpr evaluation into __constant__
// arrays. f64 Taylor sin/cos (quarter-wave reduced) matches libm to ~1 ulp;
// after f32 rounding the table differences are <=1 ulp -> output shift <=2e-5,
// far inside tolerance (absmax is dominated by the reference's f32 FFT).
// Evaluation is split across several constexpr objects so each initializer
// stays well under clang's per-expression constexpr step limit.
// ===========================================================================
constexpr double PI_D = 3.14159265358979323846264338327950288;

struct D512 { double v[512]; };
struct F512 { float v[512]; };
struct SCT2 { float sc[NA][2]; };

constexpr double cosap(double x) {   // |x| <= ~pi/2, Taylor to x^24
    double invf[13] = {};
    double f = 1.0; invf[0] = 1.0;
    for (int n = 1; n <= 12; ++n) { f *= (double)((2 * n - 1) * (2 * n)); invf[n] = 1.0 / f; }
    const double x2 = x * x;
    double r = invf[12];
    for (int n = 11; n >= 0; --n) r = invf[n] - x2 * r;
    return r;
}
constexpr double sinap(double x) {   // |x| <= ~pi/2, Taylor to x^25 (odd -> sign-correct)
    double invf[13] = {};
    double f = 1.0; invf[0] = 1.0;
    for (int n = 1; n <= 12; ++n) { f *= (double)((2 * n) * (2 * n + 1)); invf[n] = 1.0 / f; }
    const double x2 = x * x;
    double r = invf[12];
    for (int n = 11; n >= 0; --n) r = invf[n] - x2 * r;
    return x * r;
}

// cos(2*pi*ph/512) for ph in [0,512), quarter-wave reduced (exactly symmetric).
constexpr D512 make_ct() {
    D512 t{};
    for (int ph = 0; ph < 512; ++ph) {
        const int q = ph >> 7, r = ph & 127;
        double v = 0.0;
        if (q == 0)      v =  cosap(PI_D * (double)r / 256.0);
        else if (q == 1) v = -cosap(PI_D * (double)(128 - r) / 256.0);
        else if (q == 2) v = -cosap(PI_D * (double)r / 256.0);
        else             v =  cosap(PI_D * (double)(128 - r) / 256.0);
        t.v[ph] = v;
    }
    return t;
}
constexpr D512 CT = make_ct();

// ffg[o] = float( (0.5 + 2*sum_odd fodd*cos) * sinc ), even in o (exact by
// table symmetry) -> compute o<=256, mirror. Odd-index fold: terms mm and
// 255-mm are equal (n and cos both symmetric) -> 2x over mm<128.
constexpr F512 make_ffg() {
    F512 t{};
    double fv[128] = {};
    for (int mm = 0; mm < 128; ++mm) {
        const double pn = PI_D * (double)(2 * mm + 1);
        fv[mm] = -1.0 / (pn * pn);
    }
    for (int o = 0; o <= 256; ++o) {
        double s = 0.0;
        for (int mm = 0; mm < 128; ++mm)
            s += fv[mm] * CT.v[(o * (2 * mm + 1)) & 511];
        double ff = 0.5 + 4.0 * s;           // 0.5 + 2*(2*s_half)
        if (o > 0) {
            const double w = PI_D * (double)o / 512.0;   // o<=256 -> w<=pi/2
            ff *= sinap(w) / w;
        }
        t.v[o] = (float)ff;
    }
    for (int o = 257; o < 512; ++o) t.v[o] = t.v[512 - o];
    return t;
}
constexpr F512 FFG = make_ffg();

// hr[o] = (1/512) sum_k ffg[k] cos(2*pi*k*o/512); k-fold (ffg, cos even) and
// o-mirror (exact). Split the o-range across two initializers for step budget.
constexpr F512 make_hr_part(int lo, int hi) {
    F512 t{};
    for (int o = lo; o < hi; ++o) {
        double s2 = 0.0;
        for (int k = 1; k < 256; ++k)
            s2 += (double)FFG.v[k] * CT.v[(o * k) & 511];
        double s = (double)FFG.v[0] + (double)FFG.v[256] * CT.v[(o * 256) & 511] + 2.0 * s2;
        t.v[o] = (float)(s / 512.0);
    }
    return t;
}
constexpr F512 HR_A = make_hr_part(0, 129);
constexpr F512 HR_B = make_hr_part(129, 257);

constexpr F512 make_hr() {
    F512 t{};
    for (int o = 0; o < 129; ++o)   t.v[o] = HR_A.v[o];
    for (int o = 129; o < 257; ++o) t.v[o] = HR_B.v[o];
    for (int o = 257; o < 512; ++o) t.v[o] = t.v[512 - o];
    return t;
}
__constant__ F512 HRC = make_hr();

// sct[a] = (sinf(th), cosf(th)), th = float(a) * float(pi/179) -- float mult
// replicated exactly; sin/cos in f64 then rounded (<=1 ulp vs device sinf).
constexpr SCT2 make_sct() {
    SCT2 t{};
    for (int a = 0; a < NA; ++a) {
        const float thf = (float)a * (float)(PI_D / 179.0);
        const double x = (double)thf;        // in [0, ~pi]
        double sv, cv;
        if (x <= PI_D * 0.5) { sv = sinap(x);        cv =  cosap(x); }
        else                 { sv = sinap(PI_D - x); cv = -cosap(PI_D - x); }
        t.sc[a][0] = (float)sv;
        t.sc[a][1] = (float)cv;
    }
    return t;
}
__constant__ SCT2 SCT = make_sct();

// ---------------------------------------------------------------------------
// K2: one 512-thread block per angle: circular conv for ALL 4 batches with
// hr from __constant__ (s_loads), rolling register window -> ONE ds_read_b128
// per K-step per thread. Output 4-batch interleaved (FOFF4 + 4*pos + b),
// staged through LDS so global stores are coalesced dwordx4. The window-base
// table build (qbt) is fused into the tail of the same blocks.
// ---------------------------------------------------------------------------
__global__ __launch_bounds__(512) void ir_filter(const float* __restrict__ sino,
                                                 float* __restrict__ fil2,
                                                 float* __restrict__ qbt) {
    __shared__ __align__(16) float row2[4][2 * P];
    __shared__ __align__(16) float sOut[4 * P];
    const int a = blockIdx.x;
    const int t = threadIdx.x;

    const int b = t >> 7;             // batch 0..3
    const int tt = t & 127;           // outputs 4tt..4tt+3

    const float* src = sino + ((size_t)b * NA + a) * P;
    const float4 v = *(const float4*)(src + 4 * tt);
    *(float4*)&row2[b][4 * tt] = v;
    *(float4*)&row2[b][4 * tt + P] = v;
    __syncthreads();

    const int base0 = P + 4 * tt;
    float4 A = *(const float4*)&row2[b][base0];    // window floats w[0..3]
    float a0 = 0.f, a1 = 0.f, a2 = 0.f, a3 = 0.f;
    #pragma unroll 4
    for (int J = 0; J < P; J += 4) {
        const float4 Bv = *(const float4*)&row2[b][base0 - J - 4];  // w[-4..-1]
        const float h0 = HRC.v[J], h1 = HRC.v[J + 1], h2v = HRC.v[J + 2], h3 = HRC.v[J + 3];
        a0 = fmaf(h0, A.x, a0); a0 = fmaf(h1, Bv.w, a0); a0 = fmaf(h2v, Bv.z, a0); a0 = fmaf(h3, Bv.y, a0);
        a1 = fmaf(h0, A.y, a1); a1 = fmaf(h1, A.x, a1); a1 = fmaf(h2v, Bv.w, a1); a1 = fmaf(h3, Bv.z, a1);
        a2 = fmaf(h0, A.z, a2); a2 = fmaf(h1, A.y, a2); a2 = fmaf(h2v, A.x, a2); a2 = fmaf(h3, Bv.w, a2);
        a3 = fmaf(h0, A.w, a3); a3 = fmaf(h1, A.z, a3); a3 = fmaf(h2v, A.y, a3); a3 = fmaf(h3, A.x, a3);
        A = Bv;                                    // slide the register window
    }
    // interleave via LDS: float index in data region = 4*pos + b, pos = 4tt+d
    const int o0 = 16 * tt + b;
    sOut[o0]      = a0;
    sOut[o0 + 4]  = a1;
    sOut[o0 + 8]  = a2;
    sOut[o0 + 12] = a3;
    __syncthreads();

    float* frow = fil2 + (size_t)a * FS4;
    *(f4*)(frow + FOFF4 + 4 * t) = *(const f4*)(sOut + 4 * t);   // coalesced
    if (t < FOFF4) {                  // zero pads (ws re-poisoned every call)
        frow[t] = 0.f;
        frow[FOFF4 + 4 * P + t] = 0.f;
    }

    // fused window-base table for this angle (was a separate grid slice)
    const float sa = SCT.sc[a][0];
    const float ca = SCT.sc[a][1];
    #pragma unroll
    for (int i = 0; i < 2; ++i) {
        const int tile = t + 512 * i;          // by*32+bx
        const int bx = tile & 31, by = tile >> 5;
        const float xlo = (float)(240 - 16 * bx);   // min x over tile
        const float ylo = (float)(16 * by - 256);
        const float yhi = (float)(16 * by - 241);
        const float pmin = fmaf(sa, xlo, fminf(ca * ylo, ca * yhi) + 256.0f);
        const int base = ((int)floorf(pmin) - 2) & ~1;  // even, fp-slop safety
        qbt[tile * NA + a] = (float)(256 - base);
    }
}

// ---------------------------------------------------------------------------
// K3: backprojection, ALL 4 BATCHES per block, 16x16 tile (1024 blocks).
// Angle-segmented 26.9 KB window buffer, 4-batch interleave: q/j/frac math
// ONCE per pixel; two 16B LDS reads per angle feed 8 bilinear taps.
// Per-angle constants (s, c from __constant__, qb from global) are
// wave-uniform s_loads -- the LDS pipe carries only the window gather.
// ---------------------------------------------------------------------------
__global__ __launch_bounds__(256) void ir_backproject(const float* __restrict__ fil2,
                                                      const float* __restrict__ qbt,
                                                      float* __restrict__ out) {
    __shared__ __align__(16) float win[ASEG * WSF4 + 16];   // 26.9 KB + slack

    const int t = threadIdx.x;
    const int w0 = blockIdx.x * TS, h0 = blockIdx.y * TS;
    const float* qrow = qbt + (blockIdx.y * 32 + blockIdx.x) * NA;  // this tile's bases

    const int w = w0 + (t & 15);
    const int h = h0 + (t >> 4);

    const int ix = 255 - w;              // reversed x axis
    const int iy = h - 256;
    const int m = (ix * ix + iy * iy) <= 256 * 256;

    float* o0 = out + (size_t)h * P + w;

    if (__syncthreads_count(m) == 0) {   // tile fully outside circle
        o0[0] = 0.f;
        o0[P * P] = 0.f;
        o0[2 * P * P] = 0.f;
        o0[3 * P * P] = 0.f;
        return;
    }

    const float xf = (float)ix;
    const float yf = (float)iy;
    float acc0 = 0.f, acc1 = 0.f, acc2 = 0.f, acc3 = 0.f;

    #pragma unroll
    for (int seg = 0; seg < 3; ++seg) {
        const int A0 = seg * ASEG;

        // Phase B: stage this segment's 4-batch windows (16B-aligned chunks)
        for (int idx = t; idx < ASEG * WPOS; idx += 256) {
            const int al = idx / WPOS;
            const int i = idx - al * WPOS;
            const int a = A0 + al;
            const int base = 256 - (int)qrow[a];          // lane-varying -> v-load
            const int off = a * FS4 + FOFF4 + 4 * (base + i);  // 16B aligned
            const f4 vv = *(const f4*)(fil2 + off);
            *(f4*)(win + al * WSF4 + 4 * i) = vv;
        }
        __syncthreads();

        // Phase C: q = p - base in [~2, 27); j = trunc(q); f4 at 4j holds all
        // 4 batches at position j; second f4 at 4j+4 -> both taps, 4 batches.
        #pragma unroll 4
        for (int al = 0; al < ASEG; ++al) {
            const float ss = SCT.sc[A0 + al][0];          // wave-uniform -> s_load
            const float cc = SCT.sc[A0 + al][1];
            const float qb = qrow[A0 + al];               // wave-uniform -> s_load
            const float q = fmaf(xf, ss, fmaf(yf, cc, qb));
            const int j = (int)q;
            const float fr = FRACT(q);
            const float omf = 1.f - fr;
            const f4 W0 = *(const f4*)(win + al * WSF4 + 4 * j);
            const f4 W1 = *(const f4*)(win + al * WSF4 + 4 * j + 4);
            acc0 = fmaf(omf, W0.x, fmaf(fr, W1.x, acc0));
            acc1 = fmaf(omf, W0.y, fmaf(fr, W1.y, acc1));
            acc2 = fmaf(omf, W0.z, fmaf(fr, W1.z, acc2));
            acc3 = fmaf(omf, W0.w, fmaf(fr, W1.w, acc3));
        }
        if (seg < 2) __syncthreads();    // protect win before restage (uniform)
    }

    const float scale = (float)(M_PI / (2.0 * NA));
    o0[0]         = m ? acc0 * scale : 0.f;
    o0[P * P]     = m ? acc1 * scale : 0.f;
    o0[2 * P * P] = m ? acc2 * scale : 0.f;
    o0[3 * P * P] = m ? acc3 * scale : 0.f;
}

// ---------------------------------------------------------------------------
extern "C" void kernel_launch(void* const* d_in, const int* in_sizes, int n_in,
                              void* d_out, int out_size, void* d_ws, size_t ws_size,
                              hipStream_t stream) {
    const float* sino = (const float*)d_in[0];
    float* out = (float*)d_out;
    float* ws = (float*)d_ws;

    float* qbt   = ws;                        // 1024 tiles * 180 floats
    float* fil2  = ws + NTILES * NA + GUARD;  // 180*2176 floats, 16B aligned

    ir_filter<<<NA, 512, 0, stream>>>(sino, fil2, qbt);

    dim3 gridB(P / TS, P / TS, 1);            // 1024 blocks, 4 batches in-block
    ir_backproject<<<gridB, 256, 0, stream>>>(fil2, qbt, out);
}